// Round 5
// baseline (298.394 us; speedup 1.0000x reference)
//
#include <hip/hip_runtime.h>

#define BB 4
#define CC 32
#define HH 512
#define WW 512
#define PLANE ((size_t)HH * WW)

typedef float fx4 __attribute__((ext_vector_type(4)));  // native vec for NT store

// ---------------------------------------------------------------------------
// Fused deformable-conv kernel. The sample at pixel (h,w) depends ONLY on
// the offset conv output at (h,w), so conv+sample fuse pointwise: this
// removes the 8 MB off write + 8 MB read + one launch, and lets the gather
// latency of some waves hide under the conv FMAs of others (both halves are
// latency-bound, so sequential kernels paid sum; fused pays ~max).
//
// Conv part: off_x/off_y = conv3x3(x, w_off[0:2]) + b_off[0:2].
//   Thread: 4 w-px (float4) x 1 row. Block: 512w x 2 rows. Grid: 1024.
//   Edge pixels via lane shfl (only lanes 0/63 do a masked 4B edge load).
//   2-deep channel software pipeline. XCD band swizzle: each XCD owns 256
//   contiguous rows of one batch -> conv reads AND the (±1 px) gathers hit
//   the same XCD-local L2 band.
// Sample part: per pixel, the two x-corners (xi0, xi0+1) are one float2
//   gather; clamping folds into pair weights A0/A1/B0/B1 vs xL. 8 groups of
//   4 channels: 32 float2 gathers issued back-to-back, then 4 coalesced
//   float4 NT stores (write-once output stays out of L2).
// ---------------------------------------------------------------------------
__global__ __launch_bounds__(256) void deform_fused_kernel(
    const float* __restrict__ x, const float* __restrict__ w_off,
    const float* __restrict__ b_off, float* __restrict__ out) {
  const int nb = gridDim.x;                       // 1024
  const int i  = blockIdx.x;
  const int j  = (i & 7) * (nb >> 3) + (i >> 3);  // XCD band swizzle
  const int b    = j >> 8;                        // 256 row-pairs per batch
  const int row0 = (j & 255) << 1;

  const int t    = threadIdx.x;
  const int w4   = (t & 127) << 2;                // 0..508
  const int h    = row0 + (t >> 7);               // this thread: row h
  const int lane = t & 63;

  float4 a0v, a1v;                                // off_x / off_y for 4 px
  a0v.x = a0v.y = a0v.z = a0v.w = b_off[0];
  a1v.x = a1v.y = a1v.z = a1v.w = b_off[1];

  const float* xb = x + (size_t)b * CC * PLANE + (size_t)h * WW + w4;

  float4 mA[3], mB[3];                            // rows h-1..h+1, dbuf
  float  eA[3], eB[3];                            // boundary-lane extras

  auto load_ch = [&](int ci, float4* m, float* e) {
#pragma unroll
    for (int r = 0; r < 3; ++r) {
      const int hy = h - 1 + r;
      const float* q = xb + (size_t)ci * PLANE + (ptrdiff_t)(r - 1) * WW;
      if (hy >= 0 && hy < HH) {
        m[r] = *(const float4*)q;
        const float* ea = (lane == 0) ? q - 1 : q + 4;
        const bool eok = (lane == 0) ? (w4 > 0)
                                     : (lane == 63 && w4 < WW - 4);
        e[r] = eok ? *ea : 0.f;
      } else {
        m[r].x = m[r].y = m[r].z = m[r].w = 0.f;
        e[r] = 0.f;
      }
    }
  };

  auto compute_ch = [&](int ci, const float4* m, const float* e) {
    const float* wp0 = w_off + ci * 9;          // co=0: [ci][kh][kw]
    const float* wp1 = w_off + 288 + ci * 9;    // co=1
#pragma unroll
    for (int kh = 0; kh < 3; ++kh) {
      float vl = __shfl_up(m[kh].w, 1);
      if (lane == 0) vl = e[kh];
      float vr = __shfl_down(m[kh].x, 1);
      if (lane == 63) vr = e[kh];
      const float a0 = wp0[kh * 3 + 0], a1 = wp0[kh * 3 + 1], a2 = wp0[kh * 3 + 2];
      const float c0 = wp1[kh * 3 + 0], c1 = wp1[kh * 3 + 1], c2 = wp1[kh * 3 + 2];
      a0v.x += vl * a0 + m[kh].x * a1 + m[kh].y * a2;
      a0v.y += m[kh].x * a0 + m[kh].y * a1 + m[kh].z * a2;
      a0v.z += m[kh].y * a0 + m[kh].z * a1 + m[kh].w * a2;
      a0v.w += m[kh].z * a0 + m[kh].w * a1 + vr * a2;
      a1v.x += vl * c0 + m[kh].x * c1 + m[kh].y * c2;
      a1v.y += m[kh].x * c0 + m[kh].y * c1 + m[kh].z * c2;
      a1v.z += m[kh].y * c0 + m[kh].z * c1 + m[kh].w * c2;
      a1v.w += m[kh].z * c0 + m[kh].w * c1 + vr * c2;
    }
  };

  // 2-deep software pipeline over channels.
  load_ch(0, mA, eA);
  for (int ci = 0; ci < CC - 2; ci += 2) {
    load_ch(ci + 1, mB, eB);
    compute_ch(ci, mA, eA);
    load_ch(ci + 2, mA, eA);
    compute_ch(ci + 1, mB, eB);
  }
  load_ch(CC - 1, mB, eB);
  compute_ch(CC - 2, mA, eA);
  compute_ch(CC - 1, mB, eB);

  // ---- per-pixel sampling parameters (same arithmetic as verified split) --
  float A0[4], A1[4], B0[4], B1[4];
  int   r0[4], r1[4];
  const float offx[4] = {a0v.x, a0v.y, a0v.z, a0v.w};
  const float offy[4] = {a1v.x, a1v.y, a1v.z, a1v.w};
#pragma unroll
  for (int p = 0; p < 4; ++p) {
    const float ix = (float)(w4 + p) + offx[p];
    const float iy = (float)h + offy[p];
    const float x0f = floorf(ix);
    const float y0f = floorf(iy);
    const float wx1 = ix - x0f, wx0 = 1.f - wx1;
    const float wy1 = iy - y0f, wy0 = 1.f - wy1;
    const bool vx0 = (x0f >= 0.f) && (x0f <= (float)(WW - 1));
    const bool vx1 = (x0f + 1.f >= 0.f) && (x0f + 1.f <= (float)(WW - 1));
    const bool vy0 = (y0f >= 0.f) && (y0f <= (float)(HH - 1));
    const bool vy1 = (y0f + 1.f >= 0.f) && (y0f + 1.f <= (float)(HH - 1));
    const int xi0 = (int)fminf(fmaxf(x0f, 0.f), (float)(WW - 1));
    const int xi1 = (int)fminf(fmaxf(x0f + 1.f, 0.f), (float)(WW - 1));
    const int yi0 = (int)fminf(fmaxf(y0f, 0.f), (float)(HH - 1));
    const int yi1 = (int)fminf(fmaxf(y0f + 1.f, 0.f), (float)(HH - 1));
    const float w00 = wy0 * wx0 * ((vy0 && vx0) ? 1.f : 0.f);
    const float w01 = wy0 * wx1 * ((vy0 && vx1) ? 1.f : 0.f);
    const float w10 = wy1 * wx0 * ((vy1 && vx0) ? 1.f : 0.f);
    const float w11 = wy1 * wx1 * ((vy1 && vx1) ? 1.f : 0.f);
    const int xL = (int)fminf(fmaxf(x0f, 0.f), (float)(WW - 2));
    const int s0 = (xi0 > xL) ? 1 : 0;
    const int s1 = (xi1 > xL) ? 1 : 0;
    A0[p] = (s0 ? 0.f : w00) + (s1 ? 0.f : w01);
    A1[p] = (s0 ? w00 : 0.f) + (s1 ? w01 : 0.f);
    B0[p] = (s0 ? 0.f : w10) + (s1 ? 0.f : w11);
    B1[p] = (s0 ? w10 : 0.f) + (s1 ? w11 : 0.f);
    r0[p] = yi0 * WW + xL;
    r1[p] = yi1 * WW + xL;
  }

  // ---- gather + store: 8 groups of 4 channels ---------------------------
  const float* xp = x + (size_t)b * CC * PLANE;
  float* ob = out + (size_t)b * CC * PLANE + (size_t)h * WW + w4;

#pragma unroll 1
  for (int cg = 0; cg < 8; ++cg) {
    float2 t0[4][4], t1[4][4];
    const float* pc = xp;
#pragma unroll
    for (int c = 0; c < 4; ++c) {       // issue 32 float2 gathers back-to-back
#pragma unroll
      for (int p = 0; p < 4; ++p) {
        __builtin_memcpy(&t0[c][p], pc + r0[p], 8);
        __builtin_memcpy(&t1[c][p], pc + r1[p], 8);
      }
      pc += PLANE;
    }
    float* o = ob;
#pragma unroll
    for (int c = 0; c < 4; ++c) {       // consume + coalesced float4 NT store
      fx4 v;
      v.x = t0[c][0].x * A0[0] + t0[c][0].y * A1[0] + t1[c][0].x * B0[0] + t1[c][0].y * B1[0];
      v.y = t0[c][1].x * A0[1] + t0[c][1].y * A1[1] + t1[c][1].x * B0[1] + t1[c][1].y * B1[1];
      v.z = t0[c][2].x * A0[2] + t0[c][2].y * A1[2] + t1[c][2].x * B0[2] + t1[c][2].y * B1[2];
      v.w = t0[c][3].x * A0[3] + t0[c][3].y * A1[3] + t1[c][3].x * B0[3] + t1[c][3].y * B1[3];
      __builtin_nontemporal_store(v, (fx4*)o);
      o += PLANE;
    }
    xp += (size_t)4 * PLANE;
    ob += (size_t)4 * PLANE;
  }
}

extern "C" void kernel_launch(void* const* d_in, const int* in_sizes, int n_in,
                              void* d_out, int out_size, void* d_ws, size_t ws_size,
                              hipStream_t stream) {
  const float* x     = (const float*)d_in[0];
  const float* w_off = (const float*)d_in[1];
  const float* b_off = (const float*)d_in[2];
  float* out = (float*)d_out;

  deform_fused_kernel<<<1024, 256, 0, stream>>>(x, w_off, b_off, out);
}

// Round 6
// 286.168 us; speedup vs baseline: 1.0427x; 1.0427x over previous
//
#include <hip/hip_runtime.h>

#define BB 4
#define CC 32
#define HH 512
#define WW 512
#define PLANE ((size_t)HH * WW)

typedef float fx2 __attribute__((ext_vector_type(2)));  // native vec for NT store

// ---------------------------------------------------------------------------
// Fused deformable-conv kernel, v2: 2 px/thread, 2048 blocks (8 blocks/CU).
// Round-5 post-mortem: fusion at 1024 blocks sat at 23% occupancy — each
// wave serialized conv-latency + gather-latency with too few neighbors to
// overlap with. Halving per-thread work doubles resident waves/CU so the
// conv FMAs of some waves hide the gather latency of others.
//
// Conv: off_x/off_y = conv3x3(x, w_off[0:2]) + b_off[0:2].
//   Thread: 2 w-px (float2) x 1 row. Block: 256 threads = one 512-px row.
//   Grid: 2048 = 4 batches x 512 rows, XCD-band swizzled (each XCD owns a
//   256-row band -> conv reads and +-1px gathers hit XCD-local L2).
//   Edge px via lane shfl (lane l-1's .y / l+1's .x); lanes 0/63 do one
//   masked 4B edge load per row. 2-deep channel software pipeline.
// Sample: two x-corners = one float2 gather; clamp folded into pair
//   weights A0/A1/B0/B1 vs xL (verified in rounds 3/5). 8 groups of 4
//   channels: 16 float2 gathers in flight, then 4 float2 NT stores
//   (lane-stride 8B -> fully coalesced; write-once stays out of L2).
// ---------------------------------------------------------------------------
__global__ __launch_bounds__(256, 6) void deform_fused_kernel(
    const float* __restrict__ x, const float* __restrict__ w_off,
    const float* __restrict__ b_off, float* __restrict__ out) {
  const int nb = gridDim.x;                       // 2048
  const int i  = blockIdx.x;
  const int j  = (i & 7) * (nb >> 3) + (i >> 3);  // XCD band swizzle
  const int b  = j >> 9;                          // 512 rows per batch
  const int h  = j & 511;                         // this block: row h

  const int t    = threadIdx.x;
  const int w2   = t << 1;                        // 0..510
  const int lane = t & 63;

  float2 a0v, a1v;                                // off_x / off_y for 2 px
  a0v.x = a0v.y = b_off[0];
  a1v.x = a1v.y = b_off[1];

  const float* xb = x + (size_t)b * CC * PLANE + (size_t)h * WW + w2;

  float2 mA[3], mB[3];                            // rows h-1..h+1, dbuf
  float  eA[3], eB[3];                            // boundary-lane extras

  auto load_ch = [&](int ci, float2* m, float* e) {
#pragma unroll
    for (int r = 0; r < 3; ++r) {
      const int hy = h - 1 + r;
      const float* q = xb + (size_t)ci * PLANE + (ptrdiff_t)(r - 1) * WW;
      if (hy >= 0 && hy < HH) {
        m[r] = *(const float2*)q;
        // lane 0 needs q[-1] (left wave edge), lane 63 needs q[2] (right).
        const float* ea = (lane == 0) ? q - 1 : q + 2;
        const bool eok = (lane == 0) ? (w2 > 0)
                                     : (lane == 63 && w2 < WW - 2);
        e[r] = eok ? *ea : 0.f;
      } else {
        m[r].x = m[r].y = 0.f;
        e[r] = 0.f;
      }
    }
  };

  auto compute_ch = [&](int ci, const float2* m, const float* e) {
    const float* wp0 = w_off + ci * 9;          // co=0: [ci][kh][kw]
    const float* wp1 = w_off + 288 + ci * 9;    // co=1
#pragma unroll
    for (int kh = 0; kh < 3; ++kh) {
      float vl = __shfl_up(m[kh].y, 1);         // px w2-1
      if (lane == 0) vl = e[kh];
      float vr = __shfl_down(m[kh].x, 1);       // px w2+2
      if (lane == 63) vr = e[kh];
      const float a0 = wp0[kh * 3 + 0], a1 = wp0[kh * 3 + 1], a2 = wp0[kh * 3 + 2];
      const float c0 = wp1[kh * 3 + 0], c1 = wp1[kh * 3 + 1], c2 = wp1[kh * 3 + 2];
      a0v.x += vl * a0 + m[kh].x * a1 + m[kh].y * a2;
      a0v.y += m[kh].x * a0 + m[kh].y * a1 + vr * a2;
      a1v.x += vl * c0 + m[kh].x * c1 + m[kh].y * c2;
      a1v.y += m[kh].x * c0 + m[kh].y * c1 + vr * c2;
    }
  };

  // 2-deep software pipeline over channels.
  load_ch(0, mA, eA);
  for (int ci = 0; ci < CC - 2; ci += 2) {
    load_ch(ci + 1, mB, eB);
    compute_ch(ci, mA, eA);
    load_ch(ci + 2, mA, eA);
    compute_ch(ci + 1, mB, eB);
  }
  load_ch(CC - 1, mB, eB);
  compute_ch(CC - 2, mA, eA);
  compute_ch(CC - 1, mB, eB);

  // ---- per-pixel sampling parameters (same arithmetic as verified split) --
  float A0[2], A1[2], B0[2], B1[2];
  int   r0[2], r1[2];
  const float offx[2] = {a0v.x, a0v.y};
  const float offy[2] = {a1v.x, a1v.y};
#pragma unroll
  for (int p = 0; p < 2; ++p) {
    const float ix = (float)(w2 + p) + offx[p];
    const float iy = (float)h + offy[p];
    const float x0f = floorf(ix);
    const float y0f = floorf(iy);
    const float wx1 = ix - x0f, wx0 = 1.f - wx1;
    const float wy1 = iy - y0f, wy0 = 1.f - wy1;
    const bool vx0 = (x0f >= 0.f) && (x0f <= (float)(WW - 1));
    const bool vx1 = (x0f + 1.f >= 0.f) && (x0f + 1.f <= (float)(WW - 1));
    const bool vy0 = (y0f >= 0.f) && (y0f <= (float)(HH - 1));
    const bool vy1 = (y0f + 1.f >= 0.f) && (y0f + 1.f <= (float)(HH - 1));
    const int xi0 = (int)fminf(fmaxf(x0f, 0.f), (float)(WW - 1));
    const int xi1 = (int)fminf(fmaxf(x0f + 1.f, 0.f), (float)(WW - 1));
    const int yi0 = (int)fminf(fmaxf(y0f, 0.f), (float)(HH - 1));
    const int yi1 = (int)fminf(fmaxf(y0f + 1.f, 0.f), (float)(HH - 1));
    const float w00 = wy0 * wx0 * ((vy0 && vx0) ? 1.f : 0.f);
    const float w01 = wy0 * wx1 * ((vy0 && vx1) ? 1.f : 0.f);
    const float w10 = wy1 * wx0 * ((vy1 && vx0) ? 1.f : 0.f);
    const float w11 = wy1 * wx1 * ((vy1 && vx1) ? 1.f : 0.f);
    const int xL = (int)fminf(fmaxf(x0f, 0.f), (float)(WW - 2));
    const int s0 = (xi0 > xL) ? 1 : 0;
    const int s1 = (xi1 > xL) ? 1 : 0;
    A0[p] = (s0 ? 0.f : w00) + (s1 ? 0.f : w01);
    A1[p] = (s0 ? w00 : 0.f) + (s1 ? w01 : 0.f);
    B0[p] = (s0 ? 0.f : w10) + (s1 ? 0.f : w11);
    B1[p] = (s0 ? w10 : 0.f) + (s1 ? w11 : 0.f);
    r0[p] = yi0 * WW + xL;
    r1[p] = yi1 * WW + xL;
  }

  // ---- gather + store: 8 groups of 4 channels ---------------------------
  const float* xp = x + (size_t)b * CC * PLANE;
  float* ob = out + (size_t)b * CC * PLANE + (size_t)h * WW + w2;

#pragma unroll 1
  for (int cg = 0; cg < 8; ++cg) {
    float2 t0[4][2], t1[4][2];
    const float* pc = xp;
#pragma unroll
    for (int c = 0; c < 4; ++c) {       // issue 16 float2 gathers back-to-back
#pragma unroll
      for (int p = 0; p < 2; ++p) {
        __builtin_memcpy(&t0[c][p], pc + r0[p], 8);
        __builtin_memcpy(&t1[c][p], pc + r1[p], 8);
      }
      pc += PLANE;
    }
    float* o = ob;
#pragma unroll
    for (int c = 0; c < 4; ++c) {       // consume + coalesced float2 NT store
      fx2 v;
      v.x = t0[c][0].x * A0[0] + t0[c][0].y * A1[0] + t1[c][0].x * B0[0] + t1[c][0].y * B1[0];
      v.y = t0[c][1].x * A0[1] + t0[c][1].y * A1[1] + t1[c][1].x * B0[1] + t1[c][1].y * B1[1];
      __builtin_nontemporal_store(v, (fx2*)o);
      o += PLANE;
    }
    xp += (size_t)4 * PLANE;
    ob += (size_t)4 * PLANE;
  }
}

extern "C" void kernel_launch(void* const* d_in, const int* in_sizes, int n_in,
                              void* d_out, int out_size, void* d_ws, size_t ws_size,
                              hipStream_t stream) {
  const float* x     = (const float*)d_in[0];
  const float* w_off = (const float*)d_in[1];
  const float* b_off = (const float*)d_in[2];
  float* out = (float*)d_out;

  deform_fused_kernel<<<2048, 256, 0, stream>>>(x, w_off, b_off, out);
}